// Round 7
// baseline (279.777 us; speedup 1.0000x reference)
//
#include <hip/hip_runtime.h>
#include <hip/hip_bf16.h>
#include <cstdint>
#include <cstddef>

#define WS7    7
#define NHEADS 8
#define HD     32
#define CDIM   256
#define HP     133
#define NWY    19
#define NWIN   361     // 19*19 windows
#define BATCH  8
#define HIMG   128
#define TOK    49      // WS*WS tokens per window
#define MTOK   64      // padded token count
#define SHIFT3 3

typedef __attribute__((ext_vector_type(8))) short short8;
typedef __attribute__((ext_vector_type(4))) short short4v;
typedef __attribute__((ext_vector_type(4))) float f32x4;

// ---- LDS layout (byte offsets) ----
// region A: xbuf [64][264] bf16 (phase1-2)  -> attnout [64][264] bf16 (post-PV)
// region B: VT [256][VROW] bf16 (V transposed: [channel][token]), VROW=76
#define XROWB  528                         // row stride in BYTES (264 bf16)
#define VROW   76
#define VT_OFF 33792                       // 64*528
#define SMEM_BYTES (VT_OFF + 256*VROW*2)   // 72704 => 2 blocks/CU

#define QS      0.25505653712988137f       // 32^-0.5 * log2(e)
#define MASKL2 -144.26950408889634f        // -100 * log2(e)

__device__ __forceinline__ short f2bf(float f) {
  union { float f; uint32_t u; } v; v.f = f;
  uint32_t r = v.u + 0x7FFFu + ((v.u >> 16) & 1u);   // RNE
  return (short)(r >> 16);
}

__device__ __forceinline__ uint32_t pk2(float a, float b) {
  union { __hip_bfloat162 h; uint32_t u; } cv;
  cv.h = __float22bfloat162_rn(float2{a, b});
  return cv.u;
}

#if defined(__has_builtin)
#if __has_builtin(__builtin_amdgcn_exp2f)
#define EXP2F __builtin_amdgcn_exp2f
#else
#define EXP2F exp2f
#endif
#else
#define EXP2F exp2f
#endif

#if defined(__has_builtin)
#if __has_builtin(__builtin_amdgcn_mfma_f32_16x16x16bf16_1k)
#define HAVE_MFMA16 1
#endif
#endif

__device__ __forceinline__ f32x4 mfma16(short4v a, short4v b, f32x4 c) {
#ifdef HAVE_MFMA16
  return __builtin_amdgcn_mfma_f32_16x16x16bf16_1k(a, b, c, 0, 0, 0);
#else
  asm("v_mfma_f32_16x16x16_bf16 %0, %1, %2, %0" : "+v"(c) : "v"(a), "v"(b));
  return c;
#endif
}

// region code of a rolled-layout coordinate: 0: [0,126) 1: [126,130) 2: [130,...)
__device__ __forceinline__ int regcode(int c) { return (c < 126) ? 0 : ((c < 130) ? 1 : 2); }

__global__ void cvt_weights(const float* __restrict__ qkv_w, const float* __restrict__ proj_w,
                            short* __restrict__ qkvw_bf, short* __restrict__ projw_bf) {
  int stride = gridDim.x * blockDim.x;
  int i0 = blockIdx.x * blockDim.x + threadIdx.x;
  for (int i = i0; i < 768 * 256; i += stride) qkvw_bf[i] = f2bf(qkv_w[i]);
  for (int i = i0; i < 256 * 256; i += stride) projw_bf[i] = f2bf(proj_w[i]);
}

__global__ __launch_bounds__(512, 4) void swin_fused(
    const float* __restrict__ x, const short* __restrict__ qkvw,
    const float* __restrict__ qkv_b, const short* __restrict__ projw,
    const float* __restrict__ proj_b, float* __restrict__ out)
{
  extern __shared__ char smem[];
  const int tid  = threadIdx.x;
  const int wave = tid >> 6;
  const int lane = tid & 63;
  const int lg   = lane >> 4;   // 0..3
  const int ln   = lane & 15;   // 0..15
  const int blk  = blockIdx.x;
  const int b    = blk / NWIN;
  const int wdx  = blk - b * NWIN;
  const int wy   = wdx / NWY;
  const int wx   = wdx - wy * NWY;

  // ---- Phase 1: gather rolled/padded x window -> LDS bf16 [64][264]; rows>=49 zero ----
  {
    const int c4 = lane;   // float4 chunk 0..63
#pragma unroll
    for (int it = 0; it < 8; ++it) {
      int r = 8 * it + wave;
      uint2 v = make_uint2(0u, 0u);
      if (r < TOK) {
        int ty = r / WS7, tx = r - WS7 * (r / WS7);
        int sh = wy * WS7 + ty + SHIFT3; if (sh >= HP) sh -= HP;
        int sw = wx * WS7 + tx + SHIFT3; if (sw >= HP) sw -= HP;
        if (sh < HIMG && sw < HIMG) {
          const float4 f = *reinterpret_cast<const float4*>(
              x + (((size_t)b * (HIMG * HIMG) + sh * HIMG + sw) * CDIM + c4 * 4));
          v = make_uint2(pk2(f.x, f.y), pk2(f.z, f.w));
        }
      }
      *reinterpret_cast<uint2*>(smem + r * XROWB + c4 * 8) = v;
    }
  }
  __syncthreads();

  const int h = wave;
  const int qcol = h * HD;
  const int kcol = 256 + h * HD;
  const int vcol = 512 + h * HD;

  f32x4 acc[2][4];
  short4v qf[2][4], kf[2][4];

#define QKV_PASS(COLBASE)                                                          \
  _Pragma("unroll")                                                                \
  for (int ct = 0; ct < 2; ++ct)                                                   \
    _Pragma("unroll")                                                              \
    for (int tt = 0; tt < 4; ++tt) acc[ct][tt] = (f32x4){0, 0, 0, 0};              \
  _Pragma("unroll 2")                                                              \
  for (int ks = 0; ks < 8; ++ks) {                                                 \
    const int k0 = ks * 32 + lg * 8;                                               \
    short8 xb[4];                                                                  \
    _Pragma("unroll")                                                              \
    for (int tt = 0; tt < 4; ++tt)                                                 \
      xb[tt] = *reinterpret_cast<const short8*>(smem + (16 * tt + ln) * XROWB + k0 * 2); \
    short8 w[2];                                                                   \
    _Pragma("unroll")                                                              \
    for (int ct = 0; ct < 2; ++ct)                                                 \
      w[ct] = *reinterpret_cast<const short8*>(qkvw + (size_t)((COLBASE) + 16 * ct + ln) * CDIM + k0); \
    _Pragma("unroll")                                                              \
    for (int ct = 0; ct < 2; ++ct)                                                 \
      _Pragma("unroll")                                                            \
      for (int tt = 0; tt < 4; ++tt)                                               \
        acc[ct][tt] = __builtin_amdgcn_mfma_f32_16x16x32_bf16(w[ct], xb[tt], acc[ct][tt], 0, 0, 0); \
  }

  // ---- Pass Q: Q^T (lane=token, reg=channel); fold scale*log2e ----
  QKV_PASS(qcol)
#pragma unroll
  for (int ct = 0; ct < 2; ++ct) {
    f32x4 bias = *reinterpret_cast<const f32x4*>(qkv_b + qcol + 16 * ct + 4 * lg);
#pragma unroll
    for (int tt = 0; tt < 4; ++tt) {
      float e0 = fmaf(acc[ct][tt][0], QS, bias[0] * QS);
      float e1 = fmaf(acc[ct][tt][1], QS, bias[1] * QS);
      float e2 = fmaf(acc[ct][tt][2], QS, bias[2] * QS);
      float e3 = fmaf(acc[ct][tt][3], QS, bias[3] * QS);
      union { uint2 u; short4v s; } cv;
      cv.u = make_uint2(pk2(e0, e1), pk2(e2, e3));
      qf[ct][tt] = cv.s;
    }
  }

  // ---- Pass K ----
  QKV_PASS(kcol)
#pragma unroll
  for (int ct = 0; ct < 2; ++ct) {
    f32x4 bias = *reinterpret_cast<const f32x4*>(qkv_b + kcol + 16 * ct + 4 * lg);
#pragma unroll
    for (int tt = 0; tt < 4; ++tt) {
      union { uint2 u; short4v s; } cv;
      cv.u = make_uint2(pk2(acc[ct][tt][0] + bias[0], acc[ct][tt][1] + bias[1]),
                        pk2(acc[ct][tt][2] + bias[2], acc[ct][tt][3] + bias[3]));
      kf[ct][tt] = cv.s;
    }
  }

  // ---- Pass V: V^T -> LDS VT[channel][token], pair-writes along channel ----
  QKV_PASS(vcol)
#pragma unroll
  for (int ct = 0; ct < 2; ++ct) {
    f32x4 bias = *reinterpret_cast<const f32x4*>(qkv_b + vcol + 16 * ct + 4 * lg);
#pragma unroll
    for (int tt = 0; tt < 4; ++tt) {
      uint32_t p01 = pk2(acc[ct][tt][0] + bias[0], acc[ct][tt][1] + bias[1]);
      uint32_t p23 = pk2(acc[ct][tt][2] + bias[2], acc[ct][tt][3] + bias[3]);
      int row0 = h * HD + 16 * ct + 4 * lg;
      int col  = 16 * tt + ln;
      char* base = smem + VT_OFF + (row0 * VROW + col) * 2;
      *reinterpret_cast<short*>(base)            = (short)(p01 & 0xFFFF);
      *reinterpret_cast<short*>(base + VROW * 2) = (short)(p01 >> 16);
      *reinterpret_cast<short*>(base + VROW * 4) = (short)(p23 & 0xFFFF);
      *reinterpret_cast<short*>(base + VROW * 6) = (short)(p23 >> 16);
    }
  }
  __syncthreads();   // all waves done reading xbuf; region A becomes attnout

  // ---- Phase 3: S^T = K Q^T via 16x16x16 (keys on regs/lane-groups, queries on lanes) ----
  f32x4 s[4][4];   // [key tile][query tile]
#pragma unroll
  for (int kt = 0; kt < 4; ++kt)
#pragma unroll
    for (int qt = 0; qt < 4; ++qt) s[kt][qt] = (f32x4){0, 0, 0, 0};
#pragma unroll
  for (int step = 0; step < 2; ++step)
#pragma unroll
    for (int kt = 0; kt < 4; ++kt)
#pragma unroll
      for (int qt = 0; qt < 4; ++qt)
        s[kt][qt] = mfma16(kf[step][kt], qf[step][qt], s[kt][qt]);
  // qf/kf die here.

  // preload V fragments (per-kt B-operands): lane ln owns channel pair (2ln, 2ln+1)
  short4v vb[4][2];
#pragma unroll
  for (int kt = 0; kt < 4; ++kt) {
    int tok = 16 * kt + 4 * lg;
    vb[kt][0] = *reinterpret_cast<const short4v*>(
        smem + VT_OFF + ((h * HD + 2 * ln) * VROW + tok) * 2);
    vb[kt][1] = *reinterpret_cast<const short4v*>(
        smem + VT_OFF + ((h * HD + 2 * ln + 1) * VROW + tok) * 2);
  }

  // ---- fused softmax + PV per query tile (keeps pf footprint at 4 fragments) ----
  const bool bnd = (wy == NWY - 1) || (wx == NWY - 1);
  f32x4 o[4][2];
#pragma unroll
  for (int qt = 0; qt < 4; ++qt) {
    int q = 16 * qt + ln;
    int qcode = 0;
    if (bnd) {
      int qy = q / WS7, qx = q - WS7 * (q / WS7);
      qcode = 3 * regcode(wy * WS7 + qy) + regcode(wx * WS7 + qx);
    }
#pragma unroll
    for (int kt = 0; kt < 4; ++kt)
#pragma unroll
      for (int r = 0; r < 4; ++r) {
        int key = 16 * kt + 4 * lg + r;
        float v = s[kt][qt][r];
        if (bnd) {
          int ky = key / WS7, kx = key - WS7 * (key / WS7);
          int kc = 3 * regcode(wy * WS7 + ky) + regcode(wx * WS7 + kx);
          v += (kc != qcode) ? MASKL2 : 0.f;
        }
        if (key >= TOK) v = -1e30f;
        s[kt][qt][r] = v;
      }
    float m = -1e30f;
#pragma unroll
    for (int kt = 0; kt < 4; ++kt)
#pragma unroll
      for (int r = 0; r < 4; ++r) m = fmaxf(m, s[kt][qt][r]);
    m = fmaxf(m, __shfl_xor(m, 16));
    m = fmaxf(m, __shfl_xor(m, 32));
    float sum = 0.f;
#pragma unroll
    for (int kt = 0; kt < 4; ++kt)
#pragma unroll
      for (int r = 0; r < 4; ++r) {
        float e = EXP2F(s[kt][qt][r] - m);
        s[kt][qt][r] = e; sum += e;
      }
    sum += __shfl_xor(sum, 16);
    sum += __shfl_xor(sum, 32);
    float inv = 1.0f / sum;

    short4v pf[4];
#pragma unroll
    for (int kt = 0; kt < 4; ++kt) {
      union { uint2 u; short4v sv; } cv;
      cv.u = make_uint2(pk2(s[kt][qt][0] * inv, s[kt][qt][1] * inv),
                        pk2(s[kt][qt][2] * inv, s[kt][qt][3] * inv));
      pf[kt] = cv.sv;
    }

    o[qt][0] = (f32x4){0, 0, 0, 0};
    o[qt][1] = (f32x4){0, 0, 0, 0};
#pragma unroll
    for (int kt = 0; kt < 4; ++kt) {
      o[qt][0] = mfma16(pf[kt], vb[kt][0], o[qt][0]);
      o[qt][1] = mfma16(pf[kt], vb[kt][1], o[qt][1]);
    }
  }

  // write attnout as packed b32: row = query, cols (h*32+2ln, h*32+2ln+1)
#pragma unroll
  for (int qt = 0; qt < 4; ++qt)
#pragma unroll
    for (int r = 0; r < 4; ++r) {
      int row = 16 * qt + 4 * lg + r;
      uint32_t p = pk2(o[qt][0][r], o[qt][1][r]);
      *reinterpret_cast<uint32_t*>(smem + row * XROWB + h * 64 + 4 * ln) = p;
    }
  __syncthreads();

  // ---- Phase 4: proj GEMM (M=64, N=256, K=256); wave h computes cols h*32..h*32+31 ----
  f32x4 pacc[4][2];
#pragma unroll
  for (int mt = 0; mt < 4; ++mt)
#pragma unroll
    for (int n2 = 0; n2 < 2; ++n2) pacc[mt][n2] = (f32x4){0, 0, 0, 0};
#pragma unroll 2
  for (int ks = 0; ks < 8; ++ks) {
    int k0 = ks * 32 + lg * 8;
    short8 afr[4];
#pragma unroll
    for (int mt = 0; mt < 4; ++mt)
      afr[mt] = *reinterpret_cast<const short8*>(smem + (16 * mt + ln) * XROWB + k0 * 2);
    short8 bfr[2];
#pragma unroll
    for (int n2 = 0; n2 < 2; ++n2)
      bfr[n2] = *reinterpret_cast<const short8*>(projw + (size_t)(h * HD + 16 * n2 + ln) * CDIM + k0);
#pragma unroll
    for (int n2 = 0; n2 < 2; ++n2)
#pragma unroll
      for (int mt = 0; mt < 4; ++mt)
        pacc[mt][n2] = __builtin_amdgcn_mfma_f32_16x16x32_bf16(afr[mt], bfr[n2], pacc[mt][n2], 0, 0, 0);
  }

  // epilogue: bias + scatter (un-roll + crop)
  float pb0 = proj_b[h * HD + ln];
  float pb1 = proj_b[h * HD + 16 + ln];
#pragma unroll
  for (int mt = 0; mt < 4; ++mt)
#pragma unroll
    for (int r = 0; r < 4; ++r) {
      int t = 16 * mt + 4 * lg + r;
      if (t < TOK) {
        int ty = t / WS7, tx = t - WS7 * (t / WS7);
        int sh = wy * WS7 + ty + SHIFT3; if (sh >= HP) sh -= HP;
        int sw = wx * WS7 + tx + SHIFT3; if (sw >= HP) sw -= HP;
        if (sh < HIMG && sw < HIMG) {
          float* po = out + ((size_t)b * (HIMG * HIMG) + sh * HIMG + sw) * CDIM + h * HD + ln;
          po[0]  = pacc[mt][0][r] + pb0;
          po[16] = pacc[mt][1][r] + pb1;
        }
      }
    }
}

extern "C" void kernel_launch(void* const* d_in, const int* in_sizes, int n_in,
                              void* d_out, int out_size, void* d_ws, size_t ws_size,
                              hipStream_t stream) {
  const float* x      = (const float*)d_in[0];
  const float* qkv_w  = (const float*)d_in[1];
  const float* qkv_b  = (const float*)d_in[2];
  const float* proj_w = (const float*)d_in[3];
  const float* proj_b = (const float*)d_in[4];
  float* out          = (float*)d_out;

  short* qkvw_bf = (short*)d_ws;                               // 768*256*2 = 393216 B
  short* projw_bf = (short*)((char*)d_ws + 768 * 256 * 2);     // 256*256*2 = 131072 B

  hipLaunchKernelGGL(cvt_weights, dim3(256), dim3(256), 0, stream,
                     qkv_w, proj_w, qkvw_bf, projw_bf);

  hipFuncSetAttribute((const void*)swin_fused,
                      hipFuncAttributeMaxDynamicSharedMemorySize, SMEM_BYTES);
  hipLaunchKernelGGL(swin_fused, dim3(BATCH * NWIN), dim3(512), SMEM_BYTES, stream,
                     x, qkvw_bf, qkv_b, projw_bf, proj_b, out);
}

// Round 9
// 273.258 us; speedup vs baseline: 1.0239x; 1.0239x over previous
//
#include <hip/hip_runtime.h>
#include <hip/hip_bf16.h>
#include <cstdint>
#include <cstddef>

#define WS7    7
#define NHEADS 8
#define HD     32
#define CDIM   256
#define HP     133
#define NWY    19
#define NWIN   361     // 19*19 windows
#define BATCH  8
#define HIMG   128
#define TOK    49      // WS*WS tokens per window
#define MTOK   64      // padded token count
#define SHIFT3 3

typedef __attribute__((ext_vector_type(8))) short short8;
typedef __attribute__((ext_vector_type(4))) short short4v;
typedef __attribute__((ext_vector_type(4))) float f32x4;

// ---- LDS layout (byte offsets) ----
// region A: xbuf [64][264] bf16 (phase1-2)  -> attnout [64][264] bf16 (post-PV)
// region B: VT [256][VROW] bf16 (V transposed: [channel][token]), VROW=76
#define XROWB  528                         // row stride in BYTES (264 bf16)
#define VROW   76
#define VT_OFF 33792                       // 64*528
#define SMEM_BYTES (VT_OFF + 256*VROW*2)   // 72704 => 2 blocks/CU

#define QS      0.25505653712988137f       // 32^-0.5 * log2(e)
#define MASKL2 -144.26950408889634f        // -100 * log2(e)

__device__ __forceinline__ short f2bf(float f) {
  union { float f; uint32_t u; } v; v.f = f;
  uint32_t r = v.u + 0x7FFFu + ((v.u >> 16) & 1u);   // RNE
  return (short)(r >> 16);
}

__device__ __forceinline__ uint32_t pk2(float a, float b) {
  union { __hip_bfloat162 h; uint32_t u; } cv;
  cv.h = __float22bfloat162_rn(float2{a, b});
  return cv.u;
}

#if defined(__has_builtin)
#if __has_builtin(__builtin_amdgcn_exp2f)
#define EXP2F __builtin_amdgcn_exp2f
#else
#define EXP2F exp2f
#endif
#else
#define EXP2F exp2f
#endif

#if defined(__has_builtin)
#if __has_builtin(__builtin_amdgcn_mfma_f32_16x16x16bf16_1k)
#define HAVE_MFMA16 1
#endif
#endif

__device__ __forceinline__ f32x4 mfma16(short4v a, short4v b, f32x4 c) {
#ifdef HAVE_MFMA16
  return __builtin_amdgcn_mfma_f32_16x16x16bf16_1k(a, b, c, 0, 0, 0);
#else
  asm("v_mfma_f32_16x16x16_bf16 %0, %1, %2, %0" : "+v"(c) : "v"(a), "v"(b));
  return c;
#endif
}

// region code of a rolled-layout coordinate: 0: [0,126) 1: [126,130) 2: [130,...)
__device__ __forceinline__ int regcode(int c) { return (c < 126) ? 0 : ((c < 130) ? 1 : 2); }

__global__ void cvt_weights(const float* __restrict__ qkv_w, const float* __restrict__ proj_w,
                            short* __restrict__ qkvw_bf, short* __restrict__ projw_bf) {
  int stride = gridDim.x * blockDim.x;
  int i0 = blockIdx.x * blockDim.x + threadIdx.x;
  for (int i = i0; i < 768 * 256; i += stride) qkvw_bf[i] = f2bf(qkv_w[i]);
  for (int i = i0; i < 256 * 256; i += stride) projw_bf[i] = f2bf(proj_w[i]);
}

__global__ __launch_bounds__(512, 4) void swin_fused(
    const float* __restrict__ x, const short* __restrict__ qkvw,
    const float* __restrict__ qkv_b, const short* __restrict__ projw,
    const float* __restrict__ proj_b, float* __restrict__ out)
{
  extern __shared__ char smem[];
  const int tid  = threadIdx.x;
  const int wave = tid >> 6;
  const int lane = tid & 63;
  const int lg   = lane >> 4;   // 0..3
  const int ln   = lane & 15;   // 0..15
  const int blk  = blockIdx.x;
  const int b    = blk / NWIN;
  const int wdx  = blk - b * NWIN;
  const int wy   = wdx / NWY;
  const int wx   = wdx - wy * NWY;

  // ---- Phase 1: gather rolled/padded x window -> LDS bf16 [64][264]; rows>=49 zero ----
  {
    const int c4 = lane;   // float4 chunk 0..63
#pragma unroll
    for (int it = 0; it < 8; ++it) {
      int r = 8 * it + wave;
      uint2 v = make_uint2(0u, 0u);
      if (r < TOK) {
        int ty = r / WS7, tx = r - WS7 * (r / WS7);
        int sh = wy * WS7 + ty + SHIFT3; if (sh >= HP) sh -= HP;
        int sw = wx * WS7 + tx + SHIFT3; if (sw >= HP) sw -= HP;
        if (sh < HIMG && sw < HIMG) {
          const float4 f = *reinterpret_cast<const float4*>(
              x + (((size_t)b * (HIMG * HIMG) + sh * HIMG + sw) * CDIM + c4 * 4));
          v = make_uint2(pk2(f.x, f.y), pk2(f.z, f.w));
        }
      }
      *reinterpret_cast<uint2*>(smem + r * XROWB + c4 * 8) = v;
    }
  }
  __syncthreads();

  const int h = wave;
  const int qcol = h * HD;
  const int kcol = 256 + h * HD;
  const int vcol = 512 + h * HD;

  f32x4 acc[2][4];
  short4v qf[2][4], kf[2][4];

#define QKV_PASS(COLBASE)                                                          \
  _Pragma("unroll")                                                                \
  for (int ct = 0; ct < 2; ++ct)                                                   \
    _Pragma("unroll")                                                              \
    for (int tt = 0; tt < 4; ++tt) acc[ct][tt] = (f32x4){0, 0, 0, 0};              \
  _Pragma("unroll 2")                                                              \
  for (int ks = 0; ks < 8; ++ks) {                                                 \
    const int k0 = ks * 32 + lg * 8;                                               \
    short8 xb[4];                                                                  \
    _Pragma("unroll")                                                              \
    for (int tt = 0; tt < 4; ++tt)                                                 \
      xb[tt] = *reinterpret_cast<const short8*>(smem + (16 * tt + ln) * XROWB + k0 * 2); \
    short8 w[2];                                                                   \
    _Pragma("unroll")                                                              \
    for (int ct = 0; ct < 2; ++ct)                                                 \
      w[ct] = *reinterpret_cast<const short8*>(qkvw + (size_t)((COLBASE) + 16 * ct + ln) * CDIM + k0); \
    _Pragma("unroll")                                                              \
    for (int ct = 0; ct < 2; ++ct)                                                 \
      _Pragma("unroll")                                                            \
      for (int tt = 0; tt < 4; ++tt)                                               \
        acc[ct][tt] = __builtin_amdgcn_mfma_f32_16x16x32_bf16(w[ct], xb[tt], acc[ct][tt], 0, 0, 0); \
  }

  // ---- Pass Q: Q^T (lane=token, reg=channel); fold scale*log2e ----
  QKV_PASS(qcol)
#pragma unroll
  for (int ct = 0; ct < 2; ++ct) {
    f32x4 bias = *reinterpret_cast<const f32x4*>(qkv_b + qcol + 16 * ct + 4 * lg);
#pragma unroll
    for (int tt = 0; tt < 4; ++tt) {
      float e0 = fmaf(acc[ct][tt][0], QS, bias[0] * QS);
      float e1 = fmaf(acc[ct][tt][1], QS, bias[1] * QS);
      float e2 = fmaf(acc[ct][tt][2], QS, bias[2] * QS);
      float e3 = fmaf(acc[ct][tt][3], QS, bias[3] * QS);
      union { uint2 u; short4v s; } cv;
      cv.u = make_uint2(pk2(e0, e1), pk2(e2, e3));
      qf[ct][tt] = cv.s;
    }
  }

  // ---- Pass K ----
  QKV_PASS(kcol)
#pragma unroll
  for (int ct = 0; ct < 2; ++ct) {
    f32x4 bias = *reinterpret_cast<const f32x4*>(qkv_b + kcol + 16 * ct + 4 * lg);
#pragma unroll
    for (int tt = 0; tt < 4; ++tt) {
      union { uint2 u; short4v s; } cv;
      cv.u = make_uint2(pk2(acc[ct][tt][0] + bias[0], acc[ct][tt][1] + bias[1]),
                        pk2(acc[ct][tt][2] + bias[2], acc[ct][tt][3] + bias[3]));
      kf[ct][tt] = cv.s;
    }
  }

  // ---- Pass V: V^T -> LDS VT[channel][token], pair-writes along channel ----
  QKV_PASS(vcol)
#pragma unroll
  for (int ct = 0; ct < 2; ++ct) {
    f32x4 bias = *reinterpret_cast<const f32x4*>(qkv_b + vcol + 16 * ct + 4 * lg);
#pragma unroll
    for (int tt = 0; tt < 4; ++tt) {
      uint32_t p01 = pk2(acc[ct][tt][0] + bias[0], acc[ct][tt][1] + bias[1]);
      uint32_t p23 = pk2(acc[ct][tt][2] + bias[2], acc[ct][tt][3] + bias[3]);
      int row0 = h * HD + 16 * ct + 4 * lg;
      int col  = 16 * tt + ln;
      char* base = smem + VT_OFF + (row0 * VROW + col) * 2;
      *reinterpret_cast<short*>(base)            = (short)(p01 & 0xFFFF);
      *reinterpret_cast<short*>(base + VROW * 2) = (short)(p01 >> 16);
      *reinterpret_cast<short*>(base + VROW * 4) = (short)(p23 & 0xFFFF);
      *reinterpret_cast<short*>(base + VROW * 6) = (short)(p23 >> 16);
    }
  }
  __syncthreads();   // all waves done reading xbuf; region A becomes attnout

  // preload V fragments (per-kt B-operands): lane ln owns channel pair (2ln, 2ln+1)
  short4v vb[4][2];
#pragma unroll
  for (int kt = 0; kt < 4; ++kt) {
    int tok = 16 * kt + 4 * lg;
    vb[kt][0] = *reinterpret_cast<const short4v*>(
        smem + VT_OFF + ((h * HD + 2 * ln) * VROW + tok) * 2);
    vb[kt][1] = *reinterpret_cast<const short4v*>(
        smem + VT_OFF + ((h * HD + 2 * ln + 1) * VROW + tok) * 2);
  }

  // ---- Phase 3 (qt-major): per query tile: QK^T -> softmax -> PV -> LDS write ----
  // Never holds the full 64x64 S tile: peak live = qf/kf(32) + vb(16) + sq(16) + o(8) + pf(8).
  const bool bnd = (wy == NWY - 1) || (wx == NWY - 1);
#pragma unroll
  for (int qt = 0; qt < 4; ++qt) {
    f32x4 sq[4];   // S^T[keys 16kt+4lg+r][query 16qt+ln]
#pragma unroll
    for (int kt = 0; kt < 4; ++kt) sq[kt] = (f32x4){0, 0, 0, 0};
#pragma unroll
    for (int step = 0; step < 2; ++step)
#pragma unroll
      for (int kt = 0; kt < 4; ++kt)
        sq[kt] = mfma16(kf[step][kt], qf[step][qt], sq[kt]);

    int q = 16 * qt + ln;
    int qcode = 0;
    if (bnd) {
      int qy = q / WS7, qx = q - WS7 * (q / WS7);
      qcode = 3 * regcode(wy * WS7 + qy) + regcode(wx * WS7 + qx);
    }
#pragma unroll
    for (int kt = 0; kt < 4; ++kt)
#pragma unroll
      for (int r = 0; r < 4; ++r) {
        int key = 16 * kt + 4 * lg + r;
        float v = sq[kt][r];
        if (bnd) {
          int ky = key / WS7, kx = key - WS7 * (key / WS7);
          int kc = 3 * regcode(wy * WS7 + ky) + regcode(wx * WS7 + kx);
          v += (kc != qcode) ? MASKL2 : 0.f;
        }
        if (key >= TOK) v = -1e30f;
        sq[kt][r] = v;
      }
    float m = -1e30f;
#pragma unroll
    for (int kt = 0; kt < 4; ++kt)
#pragma unroll
      for (int r = 0; r < 4; ++r) m = fmaxf(m, sq[kt][r]);
    m = fmaxf(m, __shfl_xor(m, 16));
    m = fmaxf(m, __shfl_xor(m, 32));
    float sum = 0.f;
#pragma unroll
    for (int kt = 0; kt < 4; ++kt)
#pragma unroll
      for (int r = 0; r < 4; ++r) {
        float e = EXP2F(sq[kt][r] - m);
        sq[kt][r] = e; sum += e;
      }
    sum += __shfl_xor(sum, 16);
    sum += __shfl_xor(sum, 32);
    float inv = 1.0f / sum;

    short4v pf[4];
#pragma unroll
    for (int kt = 0; kt < 4; ++kt) {
      union { uint2 u; short4v sv; } cv;
      cv.u = make_uint2(pk2(sq[kt][0] * inv, sq[kt][1] * inv),
                        pk2(sq[kt][2] * inv, sq[kt][3] * inv));
      pf[kt] = cv.sv;
    }

    f32x4 o0 = (f32x4){0, 0, 0, 0};
    f32x4 o1 = (f32x4){0, 0, 0, 0};
#pragma unroll
    for (int kt = 0; kt < 4; ++kt) {
      o0 = mfma16(pf[kt], vb[kt][0], o0);
      o1 = mfma16(pf[kt], vb[kt][1], o1);
    }

    // write this qt's attnout rows immediately (packed b32: cols h*32+2ln, +1)
#pragma unroll
    for (int r = 0; r < 4; ++r) {
      int row = 16 * qt + 4 * lg + r;
      *reinterpret_cast<uint32_t*>(smem + row * XROWB + h * 64 + 4 * ln) = pk2(o0[r], o1[r]);
    }
  }
  __syncthreads();

  // ---- Phase 4: proj GEMM (M=64, N=256, K=256); wave h computes cols h*32..h*32+31 ----
  f32x4 pacc[4][2];
#pragma unroll
  for (int mt = 0; mt < 4; ++mt)
#pragma unroll
    for (int n2 = 0; n2 < 2; ++n2) pacc[mt][n2] = (f32x4){0, 0, 0, 0};
#pragma unroll 2
  for (int ks = 0; ks < 8; ++ks) {
    int k0 = ks * 32 + lg * 8;
    short8 afr[4];
#pragma unroll
    for (int mt = 0; mt < 4; ++mt)
      afr[mt] = *reinterpret_cast<const short8*>(smem + (16 * mt + ln) * XROWB + k0 * 2);
    short8 bfr[2];
#pragma unroll
    for (int n2 = 0; n2 < 2; ++n2)
      bfr[n2] = *reinterpret_cast<const short8*>(projw + (size_t)(h * HD + 16 * n2 + ln) * CDIM + k0);
#pragma unroll
    for (int n2 = 0; n2 < 2; ++n2)
#pragma unroll
      for (int mt = 0; mt < 4; ++mt)
        pacc[mt][n2] = __builtin_amdgcn_mfma_f32_16x16x32_bf16(afr[mt], bfr[n2], pacc[mt][n2], 0, 0, 0);
  }

  // epilogue: bias + scatter (un-roll + crop)
  float pb0 = proj_b[h * HD + ln];
  float pb1 = proj_b[h * HD + 16 + ln];
#pragma unroll
  for (int mt = 0; mt < 4; ++mt)
#pragma unroll
    for (int r = 0; r < 4; ++r) {
      int t = 16 * mt + 4 * lg + r;
      if (t < TOK) {
        int ty = t / WS7, tx = t - WS7 * (t / WS7);
        int sh = wy * WS7 + ty + SHIFT3; if (sh >= HP) sh -= HP;
        int sw = wx * WS7 + tx + SHIFT3; if (sw >= HP) sw -= HP;
        if (sh < HIMG && sw < HIMG) {
          float* po = out + ((size_t)b * (HIMG * HIMG) + sh * HIMG + sw) * CDIM + h * HD + ln;
          po[0]  = pacc[mt][0][r] + pb0;
          po[16] = pacc[mt][1][r] + pb1;
        }
      }
    }
}

extern "C" void kernel_launch(void* const* d_in, const int* in_sizes, int n_in,
                              void* d_out, int out_size, void* d_ws, size_t ws_size,
                              hipStream_t stream) {
  const float* x      = (const float*)d_in[0];
  const float* qkv_w  = (const float*)d_in[1];
  const float* qkv_b  = (const float*)d_in[2];
  const float* proj_w = (const float*)d_in[3];
  const float* proj_b = (const float*)d_in[4];
  float* out          = (float*)d_out;

  short* qkvw_bf = (short*)d_ws;                               // 768*256*2 = 393216 B
  short* projw_bf = (short*)((char*)d_ws + 768 * 256 * 2);     // 256*256*2 = 131072 B

  hipLaunchKernelGGL(cvt_weights, dim3(256), dim3(256), 0, stream,
                     qkv_w, proj_w, qkvw_bf, projw_bf);

  hipFuncSetAttribute((const void*)swin_fused,
                      hipFuncAttributeMaxDynamicSharedMemorySize, SMEM_BYTES);
  hipLaunchKernelGGL(swin_fused, dim3(BATCH * NWIN), dim3(512), SMEM_BYTES, stream,
                     x, qkvw_bf, qkv_b, projw_bf, proj_b, out);
}

// Round 10
// 234.000 us; speedup vs baseline: 1.1956x; 1.1678x over previous
//
#include <hip/hip_runtime.h>
#include <hip/hip_bf16.h>
#include <cstdint>
#include <cstddef>

#define WS7    7
#define NHEADS 8
#define HD     32
#define CDIM   256
#define HP     133
#define NWY    19
#define NWIN   361     // 19*19 windows
#define BATCH  8
#define HIMG   128
#define TOK    49      // WS*WS tokens per window
#define MTOK   64      // padded token count
#define SHIFT3 3

typedef __attribute__((ext_vector_type(8))) short short8;
typedef __attribute__((ext_vector_type(4))) short short4v;
typedef __attribute__((ext_vector_type(4))) float f32x4;

// ---- LDS layout (byte offsets) ----
// region A: xbuf [64][264] bf16 (phase1-2)  -> attnout [64][264] bf16 (post-QKV)
// region B: VT [256][VROW] bf16 (V transposed: [channel][token]), VROW=76
#define XROWB  528                         // row stride in BYTES (264 bf16)
#define VROW   76
#define VT_OFF 33792                       // 64*528
#define SMEM_BYTES (VT_OFF + 256*VROW*2)   // 72704 => 2 blocks/CU

#define QS      0.25505653712988137f       // 32^-0.5 * log2(e)
#define MASKL2 -144.26950408889634f        // -100 * log2(e)

__device__ __forceinline__ short f2bf(float f) {
  union { float f; uint32_t u; } v; v.f = f;
  uint32_t r = v.u + 0x7FFFu + ((v.u >> 16) & 1u);   // RNE
  return (short)(r >> 16);
}

__device__ __forceinline__ uint32_t pk2(float a, float b) {
  union { __hip_bfloat162 h; uint32_t u; } cv;
  cv.h = __float22bfloat162_rn(float2{a, b});
  return cv.u;
}

#if defined(__has_builtin)
#if __has_builtin(__builtin_amdgcn_exp2f)
#define EXP2F __builtin_amdgcn_exp2f
#else
#define EXP2F exp2f
#endif
#else
#define EXP2F exp2f
#endif

#if defined(__has_builtin)
#if __has_builtin(__builtin_amdgcn_mfma_f32_16x16x16bf16_1k)
#define HAVE_MFMA16 1
#endif
#endif

__device__ __forceinline__ f32x4 mfma16(short4v a, short4v b, f32x4 c) {
#ifdef HAVE_MFMA16
  return __builtin_amdgcn_mfma_f32_16x16x16bf16_1k(a, b, c, 0, 0, 0);
#else
  asm("v_mfma_f32_16x16x16_bf16 %0, %1, %2, %0" : "+v"(c) : "v"(a), "v"(b));
  return c;
#endif
}

// region code of a rolled-layout coordinate: 0: [0,126) 1: [126,130) 2: [130,...)
__device__ __forceinline__ int regcode(int c) { return (c < 126) ? 0 : ((c < 130) ? 1 : 2); }

__global__ void cvt_weights(const float* __restrict__ qkv_w, const float* __restrict__ proj_w,
                            short* __restrict__ qkvw_bf, short* __restrict__ projw_bf) {
  int stride = gridDim.x * blockDim.x;
  int i0 = blockIdx.x * blockDim.x + threadIdx.x;
  for (int i = i0; i < 768 * 256; i += stride) qkvw_bf[i] = f2bf(qkv_w[i]);
  for (int i = i0; i < 256 * 256; i += stride) projw_bf[i] = f2bf(proj_w[i]);
}

__global__ __launch_bounds__(512, 4) void swin_fused(
    const float* __restrict__ x, const short* __restrict__ qkvw,
    const float* __restrict__ qkv_b, const short* __restrict__ projw,
    const float* __restrict__ proj_b, float* __restrict__ out)
{
  extern __shared__ char smem[];
  const int tid  = threadIdx.x;
  const int wave = tid >> 6;
  const int lane = tid & 63;
  const int lg   = lane >> 4;   // 0..3
  const int ln   = lane & 15;   // 0..15
  const int blk  = blockIdx.x;
  const int b    = blk / NWIN;
  const int wdx  = blk - b * NWIN;
  const int wy   = wdx / NWY;
  const int wx   = wdx - wy * NWY;

  // ---- Phase 1: gather rolled/padded x window -> LDS bf16 [64][264]; rows>=49 zero ----
  {
    const int c4 = lane;   // float4 chunk 0..63
#pragma unroll
    for (int it = 0; it < 8; ++it) {
      int r = 8 * it + wave;
      uint2 v = make_uint2(0u, 0u);
      if (r < TOK) {
        int ty = r / WS7, tx = r - WS7 * (r / WS7);
        int sh = wy * WS7 + ty + SHIFT3; if (sh >= HP) sh -= HP;
        int sw = wx * WS7 + tx + SHIFT3; if (sw >= HP) sw -= HP;
        if (sh < HIMG && sw < HIMG) {
          const float4 f = *reinterpret_cast<const float4*>(
              x + (((size_t)b * (HIMG * HIMG) + sh * HIMG + sw) * CDIM + c4 * 4));
          v = make_uint2(pk2(f.x, f.y), pk2(f.z, f.w));
        }
      }
      *reinterpret_cast<uint2*>(smem + r * XROWB + c4 * 8) = v;
    }
  }
  __syncthreads();

  const int h = wave;
  const int qcol = h * HD;
  const int kcol = 256 + h * HD;
  const int vcol = 512 + h * HD;

  f32x4 acc[2][4];
  short4v qf[2][4], kf[2][4];

#define QKV_PASS(COLBASE)                                                          \
  _Pragma("unroll")                                                                \
  for (int ct = 0; ct < 2; ++ct)                                                   \
    _Pragma("unroll")                                                              \
    for (int tt = 0; tt < 4; ++tt) acc[ct][tt] = (f32x4){0, 0, 0, 0};              \
  _Pragma("unroll 2")                                                              \
  for (int ks = 0; ks < 8; ++ks) {                                                 \
    const int k0 = ks * 32 + lg * 8;                                               \
    short8 xb[4];                                                                  \
    _Pragma("unroll")                                                              \
    for (int tt = 0; tt < 4; ++tt)                                                 \
      xb[tt] = *reinterpret_cast<const short8*>(smem + (16 * tt + ln) * XROWB + k0 * 2); \
    short8 w[2];                                                                   \
    _Pragma("unroll")                                                              \
    for (int ct = 0; ct < 2; ++ct)                                                 \
      w[ct] = *reinterpret_cast<const short8*>(qkvw + (size_t)((COLBASE) + 16 * ct + ln) * CDIM + k0); \
    _Pragma("unroll")                                                              \
    for (int ct = 0; ct < 2; ++ct)                                                 \
      _Pragma("unroll")                                                            \
      for (int tt = 0; tt < 4; ++tt)                                               \
        acc[ct][tt] = __builtin_amdgcn_mfma_f32_16x16x32_bf16(w[ct], xb[tt], acc[ct][tt], 0, 0, 0); \
  }

  // ---- Pass V (FIRST: nothing long-lived afterwards): V^T -> LDS VT[channel][token] ----
  // VT rows h*HD..h*HD+31 are private to wave h (written and read only by it) -> no barrier.
  QKV_PASS(vcol)
#pragma unroll
  for (int ct = 0; ct < 2; ++ct) {
    f32x4 bias = *reinterpret_cast<const f32x4*>(qkv_b + vcol + 16 * ct + 4 * lg);
#pragma unroll
    for (int tt = 0; tt < 4; ++tt) {
      uint32_t p01 = pk2(acc[ct][tt][0] + bias[0], acc[ct][tt][1] + bias[1]);
      uint32_t p23 = pk2(acc[ct][tt][2] + bias[2], acc[ct][tt][3] + bias[3]);
      int row0 = h * HD + 16 * ct + 4 * lg;
      int col  = 16 * tt + ln;
      char* base = smem + VT_OFF + (row0 * VROW + col) * 2;
      *reinterpret_cast<short*>(base)            = (short)(p01 & 0xFFFF);
      *reinterpret_cast<short*>(base + VROW * 2) = (short)(p01 >> 16);
      *reinterpret_cast<short*>(base + VROW * 4) = (short)(p23 & 0xFFFF);
      *reinterpret_cast<short*>(base + VROW * 6) = (short)(p23 >> 16);
    }
  }

  // ---- Pass K: K^T -> kf (only kf spans the next pass) ----
  QKV_PASS(kcol)
#pragma unroll
  for (int ct = 0; ct < 2; ++ct) {
    f32x4 bias = *reinterpret_cast<const f32x4*>(qkv_b + kcol + 16 * ct + 4 * lg);
#pragma unroll
    for (int tt = 0; tt < 4; ++tt) {
      union { uint2 u; short4v s; } cv;
      cv.u = make_uint2(pk2(acc[ct][tt][0] + bias[0], acc[ct][tt][1] + bias[1]),
                        pk2(acc[ct][tt][2] + bias[2], acc[ct][tt][3] + bias[3]));
      kf[ct][tt] = cv.s;
    }
  }

  // ---- Pass Q (LAST: qf produced immediately before use); fold scale*log2e ----
  QKV_PASS(qcol)
#pragma unroll
  for (int ct = 0; ct < 2; ++ct) {
    f32x4 bias = *reinterpret_cast<const f32x4*>(qkv_b + qcol + 16 * ct + 4 * lg);
#pragma unroll
    for (int tt = 0; tt < 4; ++tt) {
      float e0 = fmaf(acc[ct][tt][0], QS, bias[0] * QS);
      float e1 = fmaf(acc[ct][tt][1], QS, bias[1] * QS);
      float e2 = fmaf(acc[ct][tt][2], QS, bias[2] * QS);
      float e3 = fmaf(acc[ct][tt][3], QS, bias[3] * QS);
      union { uint2 u; short4v s; } cv;
      cv.u = make_uint2(pk2(e0, e1), pk2(e2, e3));
      qf[ct][tt] = cv.s;
    }
  }
  __syncthreads();   // all waves done reading xbuf; region A becomes attnout

  // ---- Phase 3 (qt-major): per query tile: QK^T -> softmax -> PV -> LDS write ----
  const bool bnd = (wy == NWY - 1) || (wx == NWY - 1);
#pragma unroll
  for (int qt = 0; qt < 4; ++qt) {
    f32x4 sq[4];   // S^T[keys 16kt+4lg+r][query 16qt+ln]
#pragma unroll
    for (int kt = 0; kt < 4; ++kt) sq[kt] = (f32x4){0, 0, 0, 0};
#pragma unroll
    for (int step = 0; step < 2; ++step)
#pragma unroll
      for (int kt = 0; kt < 4; ++kt)
        sq[kt] = mfma16(kf[step][kt], qf[step][qt], sq[kt]);

    int q = 16 * qt + ln;
    int qcode = 0;
    if (bnd) {
      int qy = q / WS7, qx = q - WS7 * (q / WS7);
      qcode = 3 * regcode(wy * WS7 + qy) + regcode(wx * WS7 + qx);
    }
#pragma unroll
    for (int kt = 0; kt < 4; ++kt)
#pragma unroll
      for (int r = 0; r < 4; ++r) {
        int key = 16 * kt + 4 * lg + r;
        float v = sq[kt][r];
        if (bnd) {
          int ky = key / WS7, kx = key - WS7 * (key / WS7);
          int kc = 3 * regcode(wy * WS7 + ky) + regcode(wx * WS7 + kx);
          v += (kc != qcode) ? MASKL2 : 0.f;
        }
        if (key >= TOK) v = -1e30f;
        sq[kt][r] = v;
      }
    float m = -1e30f;
#pragma unroll
    for (int kt = 0; kt < 4; ++kt)
#pragma unroll
      for (int r = 0; r < 4; ++r) m = fmaxf(m, sq[kt][r]);
    m = fmaxf(m, __shfl_xor(m, 16));
    m = fmaxf(m, __shfl_xor(m, 32));
    float sum = 0.f;
#pragma unroll
    for (int kt = 0; kt < 4; ++kt)
#pragma unroll
      for (int r = 0; r < 4; ++r) {
        float e = EXP2F(sq[kt][r] - m);
        sq[kt][r] = e; sum += e;
      }
    sum += __shfl_xor(sum, 16);
    sum += __shfl_xor(sum, 32);
    float inv = 1.0f / sum;

    short4v pf[4];
#pragma unroll
    for (int kt = 0; kt < 4; ++kt) {
      union { uint2 u; short4v sv; } cv;
      cv.u = make_uint2(pk2(sq[kt][0] * inv, sq[kt][1] * inv),
                        pk2(sq[kt][2] * inv, sq[kt][3] * inv));
      pf[kt] = cv.sv;
    }

    // PV: V fragments loaded from LDS in-loop (VT rows are wave-private)
    f32x4 o0 = (f32x4){0, 0, 0, 0};
    f32x4 o1 = (f32x4){0, 0, 0, 0};
#pragma unroll
    for (int kt = 0; kt < 4; ++kt) {
      int tok = 16 * kt + 4 * lg;
      short4v vb0 = *reinterpret_cast<const short4v*>(
          smem + VT_OFF + ((h * HD + 2 * ln) * VROW + tok) * 2);
      short4v vb1 = *reinterpret_cast<const short4v*>(
          smem + VT_OFF + ((h * HD + 2 * ln + 1) * VROW + tok) * 2);
      o0 = mfma16(pf[kt], vb0, o0);
      o1 = mfma16(pf[kt], vb1, o1);
    }

    // write this qt's attnout rows immediately (packed b32: cols h*32+2ln, +1)
#pragma unroll
    for (int r = 0; r < 4; ++r) {
      int row = 16 * qt + 4 * lg + r;
      *reinterpret_cast<uint32_t*>(smem + row * XROWB + h * 64 + 4 * ln) = pk2(o0[r], o1[r]);
    }
  }
  __syncthreads();

  // ---- Phase 4: proj GEMM (M=64, N=256, K=256); wave h computes cols h*32..h*32+31 ----
  f32x4 pacc[4][2];
#pragma unroll
  for (int mt = 0; mt < 4; ++mt)
#pragma unroll
    for (int n2 = 0; n2 < 2; ++n2) pacc[mt][n2] = (f32x4){0, 0, 0, 0};
#pragma unroll 2
  for (int ks = 0; ks < 8; ++ks) {
    int k0 = ks * 32 + lg * 8;
    short8 afr[4];
#pragma unroll
    for (int mt = 0; mt < 4; ++mt)
      afr[mt] = *reinterpret_cast<const short8*>(smem + (16 * mt + ln) * XROWB + k0 * 2);
    short8 bfr[2];
#pragma unroll
    for (int n2 = 0; n2 < 2; ++n2)
      bfr[n2] = *reinterpret_cast<const short8*>(projw + (size_t)(h * HD + 16 * n2 + ln) * CDIM + k0);
#pragma unroll
    for (int n2 = 0; n2 < 2; ++n2)
#pragma unroll
      for (int mt = 0; mt < 4; ++mt)
        pacc[mt][n2] = __builtin_amdgcn_mfma_f32_16x16x32_bf16(afr[mt], bfr[n2], pacc[mt][n2], 0, 0, 0);
  }

  // epilogue: bias + scatter (un-roll + crop)
  float pb0 = proj_b[h * HD + ln];
  float pb1 = proj_b[h * HD + 16 + ln];
#pragma unroll
  for (int mt = 0; mt < 4; ++mt)
#pragma unroll
    for (int r = 0; r < 4; ++r) {
      int t = 16 * mt + 4 * lg + r;
      if (t < TOK) {
        int ty = t / WS7, tx = t - WS7 * (t / WS7);
        int sh = wy * WS7 + ty + SHIFT3; if (sh >= HP) sh -= HP;
        int sw = wx * WS7 + tx + SHIFT3; if (sw >= HP) sw -= HP;
        if (sh < HIMG && sw < HIMG) {
          float* po = out + ((size_t)b * (HIMG * HIMG) + sh * HIMG + sw) * CDIM + h * HD + ln;
          po[0]  = pacc[mt][0][r] + pb0;
          po[16] = pacc[mt][1][r] + pb1;
        }
      }
    }
}

extern "C" void kernel_launch(void* const* d_in, const int* in_sizes, int n_in,
                              void* d_out, int out_size, void* d_ws, size_t ws_size,
                              hipStream_t stream) {
  const float* x      = (const float*)d_in[0];
  const float* qkv_w  = (const float*)d_in[1];
  const float* qkv_b  = (const float*)d_in[2];
  const float* proj_w = (const float*)d_in[3];
  const float* proj_b = (const float*)d_in[4];
  float* out          = (float*)d_out;

  short* qkvw_bf = (short*)d_ws;                               // 768*256*2 = 393216 B
  short* projw_bf = (short*)((char*)d_ws + 768 * 256 * 2);     // 256*256*2 = 131072 B

  hipLaunchKernelGGL(cvt_weights, dim3(256), dim3(256), 0, stream,
                     qkv_w, proj_w, qkvw_bf, projw_bf);

  hipFuncSetAttribute((const void*)swin_fused,
                      hipFuncAttributeMaxDynamicSharedMemorySize, SMEM_BYTES);
  hipLaunchKernelGGL(swin_fused, dim3(BATCH * NWIN), dim3(512), SMEM_BYTES, stream,
                     x, qkvw_bf, qkv_b, projw_bf, proj_b, out);
}